// Round 14
// baseline (2596.739 us; speedup 1.0000x reference)
//
#include <hip/hip_runtime.h>

// LSTM V=32000 E=512 H=512 OUT=2 L=2 S=512 B=64 — persistent cooperative kernel.
// R14 = R13 + ONE fix: re-sentinel clear stores moved to AFTER poll detection
// (they used to stall the first poll check's vmcnt(0) by a full MALL store RT
// on waves 2-3, whose partials gate every phase). R13 structure otherwise
// verbatim: R10 sentinel-ring protocol (data-is-the-flag, relaxed agent
// atomics, 16 x 16KB ring/group, guarded polls), partial-sum wave remap
// (wave w owns K-slices {2w,2w+1}, MFMAs straight from polled registers,
// sAccP[8] partials, no sHB staging). 128 blocks x 512 threads, 4 groups x
// 32 ranks x 16 cols, RPB=16. L0 h-part A-frags LDS; L1-folded + L0 x-part
// A-frags VGPRs; x-projection MFMAs for t+1 in the phase-B shadow.

typedef _Float16 f16;
typedef _Float16 f16x8 __attribute__((ext_vector_type(8)));
typedef float f32x4 __attribute__((ext_vector_type(4)));
typedef unsigned int u32;
typedef unsigned long long u64;
typedef unsigned short u16;

constexpr int Hn = 512, En = 512, Bn = 64, Sn = 512, OUTn = 2;
constexpr int NG = 4, GB = 32, BS = 16, RPB = 16;
constexpr int NB = NG * GB;   // 128 blocks
constexpr int NT = 512;       // 8 waves
constexpr int RING = 16;
constexpr u32 SENT = 0xFFFFFFFFu;

// ws layout (bytes)
constexpr size_t XB_OFF = 0;                                  // f16x8 xb[NG][Sn][16][64] = 32 MB
constexpr size_t XB_SZ  = (size_t)NG * Sn * 16 * 64 * 16;
constexpr size_t RG_OFF = XB_OFF + XB_SZ;                     // ring: NG x 16 x 16 KB = 1 MB
constexpr size_t RG_SZ  = (size_t)NG * RING * 16384;

__device__ __forceinline__ float sig_(float x) { return 1.f / (1.f + expf(-x)); }

__device__ __forceinline__ void astore(u32* p, u32 v) {
  __hip_atomic_store(p, v, __ATOMIC_RELAXED, __HIP_MEMORY_SCOPE_AGENT);
}
__device__ __forceinline__ u64 aload64(const u64* p) {
  return __hip_atomic_load(p, __ATOMIC_RELAXED, __HIP_MEMORY_SCOPE_AGENT);
}
__device__ __forceinline__ bool okw(u64 x) {
  return ((u32)x != SENT) && ((u32)(x >> 32) != SENT);
}

// poll two 16B fragments (agent-scope dwordx4 pairs, sc1) until non-sentinel
__device__ __forceinline__ void poll2x(const u32* p0, const u32* p1, f16x8& a, f16x8& b) {
  union { f16x8 v; u32 d[4]; } ua, ub;
  int guard = 0;
  do {
    asm volatile("global_load_dwordx4 %0, %2, off sc1\n\t"
                 "global_load_dwordx4 %1, %3, off sc1\n\t"
                 "s_waitcnt vmcnt(0)"
                 : "=&v"(ua.v), "=&v"(ub.v) : "v"(p0), "v"(p1) : "memory");
    if ((ua.d[0] != SENT) & (ua.d[1] != SENT) & (ua.d[2] != SENT) & (ua.d[3] != SENT) &
        (ub.d[0] != SENT) & (ub.d[1] != SENT) & (ub.d[2] != SENT) & (ub.d[3] != SENT)) break;
  } while (++guard < (1 << 17));   // timeout => junk => absmax fail, no hang
  a = ua.v; b = ub.v;
}

union uf16 { f16 f; u16 u; };

// fragment-linear f16-element index for (k, col), BS=16 cols
__device__ __forceinline__ int fl_idx(int k, int col) {
  return (((k >> 5) * 64 + (((k >> 3) & 3) * 16) + col) << 3) + (k & 7);
}

// -------- pre-pass: gather emb -> fragment-linear f16 xb[g][t] --------
__global__ void __launch_bounds__(256) xb_fill(
    const int* __restrict__ texts, const float* __restrict__ emb,
    f16x8* __restrict__ xb)
{
  const int bidx = blockIdx.x;        // g*Sn + t
  const int g = bidx >> 9, t = bidx & (Sn - 1);
  const int tid = threadIdx.x;
  f16x8* dst = xb + (size_t)bidx * 1024;
  for (int slot = tid; slot < 1024; slot += 256) {
    int s = slot >> 6, sl = slot & 63, kg = sl >> 4, b = sl & 15;
    int idx = texts[t * Bn + g * BS + b];
    const float* er = emb + (size_t)idx * En + s * 32 + kg * 8;
    f16x8 v;
    #pragma unroll
    for (int j = 0; j < 8; ++j) v[j] = (f16)er[j];
    dst[slot] = v;
  }
}

__global__ void __launch_bounds__(NT) lstm_mfma(
    const float* __restrict__ Wf, const float* __restrict__ bf,
    const float* __restrict__ Wi, const float* __restrict__ bi,
    const float* __restrict__ Wo, const float* __restrict__ bo,
    const float* __restrict__ Wc, const float* __restrict__ bc,
    const float* __restrict__ Wy, const float* __restrict__ by,
    float* __restrict__ out, const f16x8* __restrict__ xb,
    u32* __restrict__ ringBase)
{
  __shared__ f16x8 sWAh[4][16][64];    // L0 h-part A-frags, 64 KB
  __shared__ float sAccP[8][64][17];   // per-wave partials, 34.8 KB
  __shared__ float sAccX[64][17];      // x-projection (full-K per mtile), 4.3 KB
  __shared__ float sBiasX[64], sBias1[64];
  __shared__ float sC[16][16];
  __shared__ float sRed[16][2][4];

  const int tid = threadIdx.x;
  const int bid = blockIdx.x;
  const int g = bid & 3;
  const int rank = bid >> 2;                // 0..31 within group
  const int w = tid >> 6, l = tid & 63;
  const int col = l & 15, rb = (l >> 4) << 2;

  const float* Wg[4] = {Wf, Wi, Wc, Wo};
  const float* Bg[4] = {bf, bi, bc, bo};

  u32* ringG = ringBase + (size_t)g * RING * 4096;   // u32 units, 16 KB per buffer
  const f16x8* xbG = xb + (size_t)g * Sn * 1024;

  // ---- prologue: L0 h-part A-frags (K=512, all 4 mtiles) into LDS ----
  for (int i = 0; i < 8; ++i) {
    int slot = tid * 8 + i;               // 4096 slots: [m4][s16][sl]
    int sl = slot & 63, ss = (slot >> 6) & 15, m4 = slot >> 10;
    const float* row = Wg[m4] + (size_t)(rank * RPB + (sl & 15)) * (En + Hn);
    int k0 = ss * 32 + (sl >> 4) * 8;
    f16x8 v;
    #pragma unroll
    for (int j = 0; j < 8; ++j) v[j] = (f16)row[k0 + j];
    sWAh[m4][ss][sl] = v;
  }
  // L1 folded A-frags in VGPRs: wave w needs s in {2w, 2w+1}, all 4 mtiles
  f16x8 afr1[4][2];
  #pragma unroll
  for (int m = 0; m < 4; ++m) {
    const float* row = Wg[m] + (size_t)(Hn + rank * RPB + (l & 15)) * (En + Hn);
    #pragma unroll
    for (int i = 0; i < 2; ++i) {
      int k0 = (2 * w + i) * 32 + (l >> 4) * 8;
      f16x8 v;
      #pragma unroll
      for (int j = 0; j < 8; ++j) v[j] = (f16)(row[k0 + j] + row[k0 + j + Hn]);
      afr1[m][i] = v;
    }
  }
  // L0 x-part A-frags in VGPRs (full 16 ksteps; waves 4..7, mtile = w-4)
  f16x8 axf[16];
  if (w >= 4) {
    const float* row = Wg[w - 4] + (size_t)(rank * RPB + (l & 15)) * (En + Hn);
    #pragma unroll
    for (int i = 0; i < 16; ++i) {
      int k0 = Hn + i * 32 + (l >> 4) * 8;
      f16x8 v;
      #pragma unroll
      for (int j = 0; j < 8; ++j) v[j] = (f16)row[k0 + j];
      axf[i] = v;
    }
  }
  if (tid < 64) {
    int gate = tid >> 4, hr = tid & 15;
    sBiasX[tid] = Bg[gate][rank * RPB + hr];
    sBias1[tid] = Bg[gate][Hn + rank * RPB + hr];
  }
  if (tid < 256) sC[tid >> 4][tid & 15] = 0.f;
  __syncthreads();

  // x-projection for t=0 (waves 4-7: mtile w-4, full K, direct cached xb reads)
  if (w >= 4) {
    f32x4 ax = {0.f, 0.f, 0.f, 0.f};
    #pragma unroll
    for (int s = 0; s < 16; ++s)
      ax = __builtin_amdgcn_mfma_f32_16x16x32_f16(axf[s], xbG[s * 64 + l], ax, 0, 0, 0);
    #pragma unroll
    for (int v = 0; v < 4; ++v) sAccX[(w - 4) * 16 + rb + v][col] = ax[v];
  }

  for (int t = 0; t < Sn; ++t) {
    u32* rdA = ringG + (size_t)((2 * t) & 15) * 4096;
    u32* wrA = ringG + (size_t)((2 * t + 1) & 15) * 4096;
    u32* clA = ringG + (size_t)((2 * t + 9) & 15) * 4096;

    // ===== phase A: layer 0, read rdA -> write wrA =====
    {
      f16x8 b0, b1;   // K-slices s=2w, 2w+1 — straight to MFMA, no LDS staging
      poll2x(rdA + (2 * w * 64 + l) * 4, rdA + ((2 * w + 1) * 64 + l) * 4, b0, b1);
      // R14 fix: re-sentinel AFTER detection — clears drain under MFMA/gates
      if (tid >= 128 && tid < 256) astore(clA + rank * 128 + (tid - 128), SENT);
      f32x4 a0 = {0.f, 0.f, 0.f, 0.f}, a1 = a0, a2 = a0, a3 = a0;
      a0 = __builtin_amdgcn_mfma_f32_16x16x32_f16(sWAh[0][2 * w][l], b0, a0, 0, 0, 0);
      a1 = __builtin_amdgcn_mfma_f32_16x16x32_f16(sWAh[1][2 * w][l], b0, a1, 0, 0, 0);
      a2 = __builtin_amdgcn_mfma_f32_16x16x32_f16(sWAh[2][2 * w][l], b0, a2, 0, 0, 0);
      a3 = __builtin_amdgcn_mfma_f32_16x16x32_f16(sWAh[3][2 * w][l], b0, a3, 0, 0, 0);
      a0 = __builtin_amdgcn_mfma_f32_16x16x32_f16(sWAh[0][2 * w + 1][l], b1, a0, 0, 0, 0);
      a1 = __builtin_amdgcn_mfma_f32_16x16x32_f16(sWAh[1][2 * w + 1][l], b1, a1, 0, 0, 0);
      a2 = __builtin_amdgcn_mfma_f32_16x16x32_f16(sWAh[2][2 * w + 1][l], b1, a2, 0, 0, 0);
      a3 = __builtin_amdgcn_mfma_f32_16x16x32_f16(sWAh[3][2 * w + 1][l], b1, a3, 0, 0, 0);
      #pragma unroll
      for (int v = 0; v < 4; ++v) {
        sAccP[w][ 0 + rb + v][col] = a0[v];
        sAccP[w][16 + rb + v][col] = a1[v];
        sAccP[w][32 + rb + v][col] = a2[v];
        sAccP[w][48 + rb + v][col] = a3[v];
      }
    }
    __syncthreads();
    if (tid < 128) {  // gates L0: 2 rows/thread, 8-partial sums, pack, store
      int q8 = tid >> 4, b = tid & 15;
      u32 pk = 0;
      #pragma unroll
      for (int j = 0; j < 2; ++j) {
        int hr = 2 * q8 + j;
        float af = sAccX[ 0 + hr][b] + sBiasX[ 0 + hr];
        float ai = sAccX[16 + hr][b] + sBiasX[16 + hr];
        float ac = sAccX[32 + hr][b] + sBiasX[32 + hr];
        float ao = sAccX[48 + hr][b] + sBiasX[48 + hr];
        #pragma unroll
        for (int ww = 0; ww < 8; ++ww) {
          af += sAccP[ww][ 0 + hr][b];
          ai += sAccP[ww][16 + hr][b];
          ac += sAccP[ww][32 + hr][b];
          ao += sAccP[ww][48 + hr][b];
        }
        float ft = sig_(af), it = sig_(ai), ch = tanhf(ac), ot = sig_(ao);
        float c = ft * sC[hr][b] + it * ch;
        sC[hr][b] = c;
        uf16 hv; hv.f = (f16)(ot * tanhf(c));
        pk |= (u32)hv.u << (16 * j);
      }
      int k0 = rank * RPB + 2 * q8;
      int slot = (k0 >> 5) * 64 + ((k0 >> 3) & 3) * 16 + b;
      astore(wrA + slot * 4 + (q8 & 3), pk);
    }

    // ===== phase B: layer 1 folded, read wrA -> write wrB =====
    u32* wrB = ringG + (size_t)((2 * t + 2) & 15) * 4096;
    u32* clB = ringG + (size_t)((2 * t + 10) & 15) * 4096;
    {
      f16x8 b0, b1;
      poll2x(wrA + (2 * w * 64 + l) * 4, wrA + ((2 * w + 1) * 64 + l) * 4, b0, b1);
      // R14 fix: re-sentinel AFTER detection
      if (tid >= 128 && tid < 256) astore(clB + rank * 128 + (tid - 128), SENT);
      f32x4 a0 = {0.f, 0.f, 0.f, 0.f}, a1 = a0, a2 = a0, a3 = a0;
      a0 = __builtin_amdgcn_mfma_f32_16x16x32_f16(afr1[0][0], b0, a0, 0, 0, 0);
      a1 = __builtin_amdgcn_mfma_f32_16x16x32_f16(afr1[1][0], b0, a1, 0, 0, 0);
      a2 = __builtin_amdgcn_mfma_f32_16x16x32_f16(afr1[2][0], b0, a2, 0, 0, 0);
      a3 = __builtin_amdgcn_mfma_f32_16x16x32_f16(afr1[3][0], b0, a3, 0, 0, 0);
      a0 = __builtin_amdgcn_mfma_f32_16x16x32_f16(afr1[0][1], b1, a0, 0, 0, 0);
      a1 = __builtin_amdgcn_mfma_f32_16x16x32_f16(afr1[1][1], b1, a1, 0, 0, 0);
      a2 = __builtin_amdgcn_mfma_f32_16x16x32_f16(afr1[2][1], b1, a2, 0, 0, 0);
      a3 = __builtin_amdgcn_mfma_f32_16x16x32_f16(afr1[3][1], b1, a3, 0, 0, 0);
      #pragma unroll
      for (int v = 0; v < 4; ++v) {
        sAccP[w][ 0 + rb + v][col] = a0[v];
        sAccP[w][16 + rb + v][col] = a1[v];
        sAccP[w][32 + rb + v][col] = a2[v];
        sAccP[w][48 + rb + v][col] = a3[v];
      }
    }
    __syncthreads();
    if (tid < 128) {  // gates L1
      int q8 = tid >> 4, b = tid & 15;
      u32 pk = 0;
      #pragma unroll
      for (int j = 0; j < 2; ++j) {
        int hr = 2 * q8 + j;
        float af = sBias1[ 0 + hr];
        float ai = sBias1[16 + hr];
        float ac = sBias1[32 + hr];
        float ao = sBias1[48 + hr];
        #pragma unroll
        for (int ww = 0; ww < 8; ++ww) {
          af += sAccP[ww][ 0 + hr][b];
          ai += sAccP[ww][16 + hr][b];
          ac += sAccP[ww][32 + hr][b];
          ao += sAccP[ww][48 + hr][b];
        }
        float ft = sig_(af), it = sig_(ai), ch = tanhf(ac), ot = sig_(ao);
        float c = ft * sC[hr][b] + it * ch;
        sC[hr][b] = c;
        uf16 hv; hv.f = (f16)(ot * tanhf(c));
        pk |= (u32)hv.u << (16 * j);
      }
      int k0 = rank * RPB + 2 * q8;
      int slot = (k0 >> 5) * 64 + ((k0 >> 3) & 3) * 16 + b;
      astore(wrB + slot * 4 + (q8 & 3), pk);
    }
    // x-projection for t+1 (waves 4-7, direct cached xb reads) — in the poll shadow
    if (w >= 4 && t + 1 < Sn) {
      const f16x8* xbt = xbG + (size_t)(t + 1) * 1024;
      f32x4 ax = {0.f, 0.f, 0.f, 0.f};
      #pragma unroll
      for (int s = 0; s < 16; ++s)
        ax = __builtin_amdgcn_mfma_f32_16x16x32_f16(axf[s], xbt[s * 64 + l], ax, 0, 0, 0);
      #pragma unroll
      for (int v = 0; v < 4; ++v) sAccX[(w - 4) * 16 + rb + v][col] = ax[v];
    }
  }

  // ---------- epilogue: y = h^T Wy^T + by (rank 0; final h = ring[1024%16] = ring[0]) ----------
  __syncthreads();
  if (rank == 0) {
    const u64* fin = (const u64*)ringG;
    u64* dst = (u64*)&sWAh[0][0][0];   // reuse LDS as staging
    for (int i = tid; i < 2048; i += NT) {
      u64 v = aload64(fin + i);
      int guard = 0;
      while (!okw(v)) { v = aload64(fin + i); if (++guard > (1 << 17)) break; }
      dst[i] = v;
    }
  }
  __syncthreads();
  if (rank == 0 && tid < 128) {
    const f16* tmp = (const f16*)&sWAh[0][0][0];
    int b = tid >> 3, o = (tid >> 2) & 1, kc = tid & 3;   // 16 x 2 x 4
    float p = 0.f;
    for (int kk = 0; kk < 128; ++kk) {
      int k = kc * 128 + kk;
      p += (float)tmp[fl_idx(k, b)] * Wy[o * Hn + k];
    }
    sRed[b][o][kc] = p;
  }
  __syncthreads();
  if (rank == 0 && tid < 32) {
    int b2 = tid >> 1, o2 = tid & 1;
    float s = by[o2];
    #pragma unroll
    for (int q = 0; q < 4; ++q) s += sRed[b2][o2][q];
    out[(g * BS + b2) * OUTn + o2] = s;
  }
}

extern "C" void kernel_launch(void* const* d_in, const int* in_sizes, int n_in,
                              void* d_out, int out_size, void* d_ws, size_t ws_size,
                              hipStream_t stream) {
  const int*   texts = (const int*)d_in[0];
  const float* emb   = (const float*)d_in[1];
  const float* Wf    = (const float*)d_in[2];
  const float* bf    = (const float*)d_in[3];
  const float* Wi    = (const float*)d_in[4];
  const float* bi    = (const float*)d_in[5];
  const float* Wo    = (const float*)d_in[6];
  const float* bo    = (const float*)d_in[7];
  const float* Wc    = (const float*)d_in[8];
  const float* bc    = (const float*)d_in[9];
  const float* Wy    = (const float*)d_in[10];
  const float* by    = (const float*)d_in[11];
  float* out = (float*)d_out;

  f16x8* xbuf     = (f16x8*)((char*)d_ws + XB_OFF);
  u32*   ringBase = (u32*)((char*)d_ws + RG_OFF);

  // ring init (captured in graph -> re-established every replay):
  // all 16 buffers sentinel, then ring[g][0] = zeros (initial h).
  hipMemsetAsync((void*)ringBase, 0xFF, RG_SZ, stream);
  for (int g = 0; g < NG; ++g)
    hipMemsetAsync((void*)((char*)ringBase + (size_t)g * RING * 16384), 0x00, 16384, stream);

  xb_fill<<<dim3(NG * Sn), dim3(256), 0, stream>>>(texts, emb, xbuf);

  void* args[] = {(void*)&Wf, (void*)&bf, (void*)&Wi, (void*)&bi,
                  (void*)&Wo, (void*)&bo, (void*)&Wc, (void*)&bc, (void*)&Wy, (void*)&by,
                  (void*)&out, (void*)&xbuf, (void*)&ringBase};
  hipLaunchCooperativeKernel((const void*)lstm_mfma, dim3(NB), dim3(NT), args, 0, stream);
}

// Round 15
// 2564.044 us; speedup vs baseline: 1.0128x; 1.0128x over previous
//
#include <hip/hip_runtime.h>

// LSTM V=32000 E=512 H=512 OUT=2 L=2 S=512 B=64 — persistent cooperative kernel.
// R15 = R13 (best: 2515us) + fast gate pipeline:
//  - sigmoid/tanh via v_exp_f32+v_rcp_f32 (4 instr vs libm's ~100s)
//  - gates on 256 threads (1 row each), h stored as u16 global_store_short
//  - sentinel check per-u16 (0xFFFF = f16 NaN; required for half-dword stores)
//  - ring clears on waves 6-7, R13's before-poll position (R14's after-poll regressed)
// R13 structure verbatim otherwise: sentinel-ring protocol (data-is-the-flag,
// relaxed agent atomics, 16 x 16KB ring/group, guarded polls), partial-sum wave
// remap (wave w owns K-slices {2w,2w+1}, MFMAs straight from polled registers,
// sAccP[8] partials). 128 blocks x 512 threads, 4 groups x 32 ranks x 16 cols.

typedef _Float16 f16;
typedef _Float16 f16x8 __attribute__((ext_vector_type(8)));
typedef float f32x4 __attribute__((ext_vector_type(4)));
typedef unsigned int u32;
typedef unsigned long long u64;
typedef unsigned short u16;

constexpr int Hn = 512, En = 512, Bn = 64, Sn = 512, OUTn = 2;
constexpr int NG = 4, GB = 32, BS = 16, RPB = 16;
constexpr int NB = NG * GB;   // 128 blocks
constexpr int NT = 512;       // 8 waves
constexpr int RING = 16;
constexpr u32 SENT = 0xFFFFFFFFu;

// ws layout (bytes)
constexpr size_t XB_OFF = 0;                                  // f16x8 xb[NG][Sn][16][64] = 32 MB
constexpr size_t XB_SZ  = (size_t)NG * Sn * 16 * 64 * 16;
constexpr size_t RG_OFF = XB_OFF + XB_SZ;                     // ring: NG x 16 x 16 KB = 1 MB
constexpr size_t RG_SZ  = (size_t)NG * RING * 16384;

// fast transcendentals: v_exp_f32 (2^x) + v_rcp_f32; ~1 ulp, correct saturation
__device__ __forceinline__ float fsig(float x) {
  return __builtin_amdgcn_rcpf(1.f + __builtin_amdgcn_exp2f(-1.4426950408889634f * x));
}
__device__ __forceinline__ float ftanh(float x) {
  float e = __builtin_amdgcn_exp2f(2.8853900817779268f * x);
  return 1.f - 2.f * __builtin_amdgcn_rcpf(e + 1.f);
}

__device__ __forceinline__ void astore(u32* p, u32 v) {
  __hip_atomic_store(p, v, __ATOMIC_RELAXED, __HIP_MEMORY_SCOPE_AGENT);
}
__device__ __forceinline__ u64 aload64(const u64* p) {
  return __hip_atomic_load(p, __ATOMIC_RELAXED, __HIP_MEMORY_SCOPE_AGENT);
}
// per-u16 validity (h stored as u16; 0xFFFF = f16 NaN sentinel)
__device__ __forceinline__ bool okd(u32 d) {
  return ((d & 0xFFFFu) != 0xFFFFu) & ((d >> 16) != 0xFFFFu);
}
__device__ __forceinline__ bool okw(u64 x) {
  return okd((u32)x) & okd((u32)(x >> 32));
}
// u16 agent-scope store (sc1), byte-enable safe within a dword
__device__ __forceinline__ void st16(u16* p, u16 v) {
  u32 vv = v;
  asm volatile("global_store_short %0, %1, off sc1" :: "v"(p), "v"(vv) : "memory");
}

// poll two 16B fragments (agent-scope dwordx4 pairs, sc1) until all u16 valid
__device__ __forceinline__ void poll2x(const u32* p0, const u32* p1, f16x8& a, f16x8& b) {
  union { f16x8 v; u32 d[4]; } ua, ub;
  int guard = 0;
  do {
    asm volatile("global_load_dwordx4 %0, %2, off sc1\n\t"
                 "global_load_dwordx4 %1, %3, off sc1\n\t"
                 "s_waitcnt vmcnt(0)"
                 : "=&v"(ua.v), "=&v"(ub.v) : "v"(p0), "v"(p1) : "memory");
    if (okd(ua.d[0]) & okd(ua.d[1]) & okd(ua.d[2]) & okd(ua.d[3]) &
        okd(ub.d[0]) & okd(ub.d[1]) & okd(ub.d[2]) & okd(ub.d[3])) break;
  } while (++guard < (1 << 17));   // timeout => junk => absmax fail, no hang
  a = ua.v; b = ub.v;
}

union uf16 { f16 f; u16 u; };

// fragment-linear f16-element index for (k, col), BS=16 cols
__device__ __forceinline__ int fl_idx(int k, int col) {
  return (((k >> 5) * 64 + (((k >> 3) & 3) * 16) + col) << 3) + (k & 7);
}

// -------- pre-pass: gather emb -> fragment-linear f16 xb[g][t] --------
__global__ void __launch_bounds__(256) xb_fill(
    const int* __restrict__ texts, const float* __restrict__ emb,
    f16x8* __restrict__ xb)
{
  const int bidx = blockIdx.x;        // g*Sn + t
  const int g = bidx >> 9, t = bidx & (Sn - 1);
  const int tid = threadIdx.x;
  f16x8* dst = xb + (size_t)bidx * 1024;
  for (int slot = tid; slot < 1024; slot += 256) {
    int s = slot >> 6, sl = slot & 63, kg = sl >> 4, b = sl & 15;
    int idx = texts[t * Bn + g * BS + b];
    const float* er = emb + (size_t)idx * En + s * 32 + kg * 8;
    f16x8 v;
    #pragma unroll
    for (int j = 0; j < 8; ++j) v[j] = (f16)er[j];
    dst[slot] = v;
  }
}

__global__ void __launch_bounds__(NT) lstm_mfma(
    const float* __restrict__ Wf, const float* __restrict__ bf,
    const float* __restrict__ Wi, const float* __restrict__ bi,
    const float* __restrict__ Wo, const float* __restrict__ bo,
    const float* __restrict__ Wc, const float* __restrict__ bc,
    const float* __restrict__ Wy, const float* __restrict__ by,
    float* __restrict__ out, const f16x8* __restrict__ xb,
    u32* __restrict__ ringBase)
{
  __shared__ f16x8 sWAh[4][16][64];    // L0 h-part A-frags, 64 KB
  __shared__ float sAccP[8][64][17];   // per-wave partials, 34.8 KB
  __shared__ float sAccX[64][17];      // x-projection (full-K per mtile), 4.3 KB
  __shared__ float sBiasX[64], sBias1[64];
  __shared__ float sC[16][16];
  __shared__ float sRed[16][2][4];

  const int tid = threadIdx.x;
  const int bid = blockIdx.x;
  const int g = bid & 3;
  const int rank = bid >> 2;                // 0..31 within group
  const int w = tid >> 6, l = tid & 63;
  const int col = l & 15, rb = (l >> 4) << 2;

  const float* Wg[4] = {Wf, Wi, Wc, Wo};
  const float* Bg[4] = {bf, bi, bc, bo};

  u32* ringG = ringBase + (size_t)g * RING * 4096;   // u32 units, 16 KB per buffer
  const f16x8* xbG = xb + (size_t)g * Sn * 1024;

  // ---- prologue: L0 h-part A-frags (K=512, all 4 mtiles) into LDS ----
  for (int i = 0; i < 8; ++i) {
    int slot = tid * 8 + i;               // 4096 slots: [m4][s16][sl]
    int sl = slot & 63, ss = (slot >> 6) & 15, m4 = slot >> 10;
    const float* row = Wg[m4] + (size_t)(rank * RPB + (sl & 15)) * (En + Hn);
    int k0 = ss * 32 + (sl >> 4) * 8;
    f16x8 v;
    #pragma unroll
    for (int j = 0; j < 8; ++j) v[j] = (f16)row[k0 + j];
    sWAh[m4][ss][sl] = v;
  }
  // L1 folded A-frags in VGPRs: wave w needs s in {2w, 2w+1}, all 4 mtiles
  f16x8 afr1[4][2];
  #pragma unroll
  for (int m = 0; m < 4; ++m) {
    const float* row = Wg[m] + (size_t)(Hn + rank * RPB + (l & 15)) * (En + Hn);
    #pragma unroll
    for (int i = 0; i < 2; ++i) {
      int k0 = (2 * w + i) * 32 + (l >> 4) * 8;
      f16x8 v;
      #pragma unroll
      for (int j = 0; j < 8; ++j) v[j] = (f16)(row[k0 + j] + row[k0 + j + Hn]);
      afr1[m][i] = v;
    }
  }
  // L0 x-part A-frags in VGPRs (full 16 ksteps; waves 4..7, mtile = w-4)
  f16x8 axf[16];
  if (w >= 4) {
    const float* row = Wg[w - 4] + (size_t)(rank * RPB + (l & 15)) * (En + Hn);
    #pragma unroll
    for (int i = 0; i < 16; ++i) {
      int k0 = Hn + i * 32 + (l >> 4) * 8;
      f16x8 v;
      #pragma unroll
      for (int j = 0; j < 8; ++j) v[j] = (f16)row[k0 + j];
      axf[i] = v;
    }
  }
  if (tid < 64) {
    int gate = tid >> 4, hr = tid & 15;
    sBiasX[tid] = Bg[gate][rank * RPB + hr];
    sBias1[tid] = Bg[gate][Hn + rank * RPB + hr];
  }
  if (tid < 256) sC[tid >> 4][tid & 15] = 0.f;
  __syncthreads();

  // x-projection for t=0 (waves 4-7: mtile w-4, full K, direct cached xb reads)
  if (w >= 4) {
    f32x4 ax = {0.f, 0.f, 0.f, 0.f};
    #pragma unroll
    for (int s = 0; s < 16; ++s)
      ax = __builtin_amdgcn_mfma_f32_16x16x32_f16(axf[s], xbG[s * 64 + l], ax, 0, 0, 0);
    #pragma unroll
    for (int v = 0; v < 4; ++v) sAccX[(w - 4) * 16 + rb + v][col] = ax[v];
  }

  for (int t = 0; t < Sn; ++t) {
    u32* rdA = ringG + (size_t)((2 * t) & 15) * 4096;
    u32* wrA = ringG + (size_t)((2 * t + 1) & 15) * 4096;
    u32* clA = ringG + (size_t)((2 * t + 9) & 15) * 4096;

    // ===== phase A: layer 0, read rdA -> write wrA =====
    if (tid >= 384) astore(clA + rank * 128 + (tid - 384), SENT);  // re-sentinel (waves 6-7)
    {
      f16x8 b0, b1;   // K-slices s=2w, 2w+1 — straight to MFMA, no LDS staging
      poll2x(rdA + (2 * w * 64 + l) * 4, rdA + ((2 * w + 1) * 64 + l) * 4, b0, b1);
      f32x4 a0 = {0.f, 0.f, 0.f, 0.f}, a1 = a0, a2 = a0, a3 = a0;
      a0 = __builtin_amdgcn_mfma_f32_16x16x32_f16(sWAh[0][2 * w][l], b0, a0, 0, 0, 0);
      a1 = __builtin_amdgcn_mfma_f32_16x16x32_f16(sWAh[1][2 * w][l], b0, a1, 0, 0, 0);
      a2 = __builtin_amdgcn_mfma_f32_16x16x32_f16(sWAh[2][2 * w][l], b0, a2, 0, 0, 0);
      a3 = __builtin_amdgcn_mfma_f32_16x16x32_f16(sWAh[3][2 * w][l], b0, a3, 0, 0, 0);
      a0 = __builtin_amdgcn_mfma_f32_16x16x32_f16(sWAh[0][2 * w + 1][l], b1, a0, 0, 0, 0);
      a1 = __builtin_amdgcn_mfma_f32_16x16x32_f16(sWAh[1][2 * w + 1][l], b1, a1, 0, 0, 0);
      a2 = __builtin_amdgcn_mfma_f32_16x16x32_f16(sWAh[2][2 * w + 1][l], b1, a2, 0, 0, 0);
      a3 = __builtin_amdgcn_mfma_f32_16x16x32_f16(sWAh[3][2 * w + 1][l], b1, a3, 0, 0, 0);
      #pragma unroll
      for (int v = 0; v < 4; ++v) {
        sAccP[w][ 0 + rb + v][col] = a0[v];
        sAccP[w][16 + rb + v][col] = a1[v];
        sAccP[w][32 + rb + v][col] = a2[v];
        sAccP[w][48 + rb + v][col] = a3[v];
      }
    }
    __syncthreads();
    if (tid < 256) {  // gates L0: 1 row/thread, fast trans, u16 store
      int hr = tid >> 4, b = tid & 15;
      float af = sAccX[ 0 + hr][b] + sBiasX[ 0 + hr];
      float ai = sAccX[16 + hr][b] + sBiasX[16 + hr];
      float ac = sAccX[32 + hr][b] + sBiasX[32 + hr];
      float ao = sAccX[48 + hr][b] + sBiasX[48 + hr];
      #pragma unroll
      for (int ww = 0; ww < 8; ++ww) {
        af += sAccP[ww][ 0 + hr][b];
        ai += sAccP[ww][16 + hr][b];
        ac += sAccP[ww][32 + hr][b];
        ao += sAccP[ww][48 + hr][b];
      }
      float ft = fsig(af), it = fsig(ai), ch = ftanh(ac), ot = fsig(ao);
      float c = ft * sC[hr][b] + it * ch;
      sC[hr][b] = c;
      uf16 hv; hv.f = (f16)(ot * ftanh(c));
      st16((u16*)wrA + fl_idx(rank * RPB + hr, b), hv.u);
    }

    // ===== phase B: layer 1 folded, read wrA -> write wrB =====
    u32* wrB = ringG + (size_t)((2 * t + 2) & 15) * 4096;
    u32* clB = ringG + (size_t)((2 * t + 10) & 15) * 4096;
    if (tid >= 384) astore(clB + rank * 128 + (tid - 384), SENT);
    {
      f16x8 b0, b1;
      poll2x(wrA + (2 * w * 64 + l) * 4, wrA + ((2 * w + 1) * 64 + l) * 4, b0, b1);
      f32x4 a0 = {0.f, 0.f, 0.f, 0.f}, a1 = a0, a2 = a0, a3 = a0;
      a0 = __builtin_amdgcn_mfma_f32_16x16x32_f16(afr1[0][0], b0, a0, 0, 0, 0);
      a1 = __builtin_amdgcn_mfma_f32_16x16x32_f16(afr1[1][0], b0, a1, 0, 0, 0);
      a2 = __builtin_amdgcn_mfma_f32_16x16x32_f16(afr1[2][0], b0, a2, 0, 0, 0);
      a3 = __builtin_amdgcn_mfma_f32_16x16x32_f16(afr1[3][0], b0, a3, 0, 0, 0);
      a0 = __builtin_amdgcn_mfma_f32_16x16x32_f16(afr1[0][1], b1, a0, 0, 0, 0);
      a1 = __builtin_amdgcn_mfma_f32_16x16x32_f16(afr1[1][1], b1, a1, 0, 0, 0);
      a2 = __builtin_amdgcn_mfma_f32_16x16x32_f16(afr1[2][1], b1, a2, 0, 0, 0);
      a3 = __builtin_amdgcn_mfma_f32_16x16x32_f16(afr1[3][1], b1, a3, 0, 0, 0);
      #pragma unroll
      for (int v = 0; v < 4; ++v) {
        sAccP[w][ 0 + rb + v][col] = a0[v];
        sAccP[w][16 + rb + v][col] = a1[v];
        sAccP[w][32 + rb + v][col] = a2[v];
        sAccP[w][48 + rb + v][col] = a3[v];
      }
    }
    __syncthreads();
    if (tid < 256) {  // gates L1
      int hr = tid >> 4, b = tid & 15;
      float af = sBias1[ 0 + hr];
      float ai = sBias1[16 + hr];
      float ac = sBias1[32 + hr];
      float ao = sBias1[48 + hr];
      #pragma unroll
      for (int ww = 0; ww < 8; ++ww) {
        af += sAccP[ww][ 0 + hr][b];
        ai += sAccP[ww][16 + hr][b];
        ac += sAccP[ww][32 + hr][b];
        ao += sAccP[ww][48 + hr][b];
      }
      float ft = fsig(af), it = fsig(ai), ch = ftanh(ac), ot = fsig(ao);
      float c = ft * sC[hr][b] + it * ch;
      sC[hr][b] = c;
      uf16 hv; hv.f = (f16)(ot * ftanh(c));
      st16((u16*)wrB + fl_idx(rank * RPB + hr, b), hv.u);
    }
    // x-projection for t+1 (waves 4-7, direct cached xb reads) — in the poll shadow
    if (w >= 4 && t + 1 < Sn) {
      const f16x8* xbt = xbG + (size_t)(t + 1) * 1024;
      f32x4 ax = {0.f, 0.f, 0.f, 0.f};
      #pragma unroll
      for (int s = 0; s < 16; ++s)
        ax = __builtin_amdgcn_mfma_f32_16x16x32_f16(axf[s], xbt[s * 64 + l], ax, 0, 0, 0);
      #pragma unroll
      for (int v = 0; v < 4; ++v) sAccX[(w - 4) * 16 + rb + v][col] = ax[v];
    }
  }

  // ---------- epilogue: y = h^T Wy^T + by (rank 0; final h = ring[1024%16] = ring[0]) ----------
  __syncthreads();
  if (rank == 0) {
    const u64* fin = (const u64*)ringG;
    u64* dst = (u64*)&sWAh[0][0][0];   // reuse LDS as staging
    for (int i = tid; i < 2048; i += NT) {
      u64 v = aload64(fin + i);
      int guard = 0;
      while (!okw(v)) { v = aload64(fin + i); if (++guard > (1 << 17)) break; }
      dst[i] = v;
    }
  }
  __syncthreads();
  if (rank == 0 && tid < 128) {
    const f16* tmp = (const f16*)&sWAh[0][0][0];
    int b = tid >> 3, o = (tid >> 2) & 1, kc = tid & 3;   // 16 x 2 x 4
    float p = 0.f;
    for (int kk = 0; kk < 128; ++kk) {
      int k = kc * 128 + kk;
      p += (float)tmp[fl_idx(k, b)] * Wy[o * Hn + k];
    }
    sRed[b][o][kc] = p;
  }
  __syncthreads();
  if (rank == 0 && tid < 32) {
    int b2 = tid >> 1, o2 = tid & 1;
    float s = by[o2];
    #pragma unroll
    for (int q = 0; q < 4; ++q) s += sRed[b2][o2][q];
    out[(g * BS + b2) * OUTn + o2] = s;
  }
}

extern "C" void kernel_launch(void* const* d_in, const int* in_sizes, int n_in,
                              void* d_out, int out_size, void* d_ws, size_t ws_size,
                              hipStream_t stream) {
  const int*   texts = (const int*)d_in[0];
  const float* emb   = (const float*)d_in[1];
  const float* Wf    = (const float*)d_in[2];
  const float* bf    = (const float*)d_in[3];
  const float* Wi    = (const float*)d_in[4];
  const float* bi    = (const float*)d_in[5];
  const float* Wo    = (const float*)d_in[6];
  const float* bo    = (const float*)d_in[7];
  const float* Wc    = (const float*)d_in[8];
  const float* bc    = (const float*)d_in[9];
  const float* Wy    = (const float*)d_in[10];
  const float* by    = (const float*)d_in[11];
  float* out = (float*)d_out;

  f16x8* xbuf     = (f16x8*)((char*)d_ws + XB_OFF);
  u32*   ringBase = (u32*)((char*)d_ws + RG_OFF);

  // ring init (captured in graph -> re-established every replay):
  // all 16 buffers sentinel, then ring[g][0] = zeros (initial h).
  hipMemsetAsync((void*)ringBase, 0xFF, RG_SZ, stream);
  for (int g = 0; g < NG; ++g)
    hipMemsetAsync((void*)((char*)ringBase + (size_t)g * RING * 16384), 0x00, 16384, stream);

  xb_fill<<<dim3(NG * Sn), dim3(256), 0, stream>>>(texts, emb, xbuf);

  void* args[] = {(void*)&Wf, (void*)&bf, (void*)&Wi, (void*)&bi,
                  (void*)&Wo, (void*)&bo, (void*)&Wc, (void*)&bc, (void*)&Wy, (void*)&by,
                  (void*)&out, (void*)&xbuf, (void*)&ringBase};
  hipLaunchCooperativeKernel((const void*)lstm_mfma, dim3(NB), dim3(NT), args, 0, stream);
}

// Round 16
// 2215.874 us; speedup vs baseline: 1.1719x; 1.1571x over previous
//
#include <hip/hip_runtime.h>

// LSTM V=32000 E=512 H=512 OUT=2 L=2 S=512 B=64 — persistent cooperative kernel.
// R16 = R13 (proven best, 2515us) + fast transcendentals ONLY.
// R13 structure verbatim: sentinel-ring protocol (data-is-the-flag, relaxed
// agent atomics, 16 x 16KB ring/group, guarded polls), partial-sum wave remap
// (wave w owns K-slices {2w,2w+1}, MFMAs straight from polled registers,
// sAccP[8] partials, no sHB staging), clears at tid 128-255 BEFORE poll,
// u32 packed h-stores (R15's u16 stores raised WRITE_SIZE and regressed).
// 128 blocks x 512 threads, 4 groups x 32 ranks x 16 cols, RPB=16.

typedef _Float16 f16;
typedef _Float16 f16x8 __attribute__((ext_vector_type(8)));
typedef float f32x4 __attribute__((ext_vector_type(4)));
typedef unsigned int u32;
typedef unsigned long long u64;
typedef unsigned short u16;

constexpr int Hn = 512, En = 512, Bn = 64, Sn = 512, OUTn = 2;
constexpr int NG = 4, GB = 32, BS = 16, RPB = 16;
constexpr int NB = NG * GB;   // 128 blocks
constexpr int NT = 512;       // 8 waves
constexpr int RING = 16;
constexpr u32 SENT = 0xFFFFFFFFu;

// ws layout (bytes)
constexpr size_t XB_OFF = 0;                                  // f16x8 xb[NG][Sn][16][64] = 32 MB
constexpr size_t XB_SZ  = (size_t)NG * Sn * 16 * 64 * 16;
constexpr size_t RG_OFF = XB_OFF + XB_SZ;                     // ring: NG x 16 x 16 KB = 1 MB
constexpr size_t RG_SZ  = (size_t)NG * RING * 16384;

// fast transcendentals: v_exp_f32 (2^x) + v_rcp_f32; ~1 ulp, correct saturation
__device__ __forceinline__ float fsig(float x) {
  return __builtin_amdgcn_rcpf(1.f + __builtin_amdgcn_exp2f(-1.4426950408889634f * x));
}
__device__ __forceinline__ float ftanh(float x) {
  float e = __builtin_amdgcn_exp2f(2.8853900817779268f * x);
  return 1.f - 2.f * __builtin_amdgcn_rcpf(e + 1.f);
}

__device__ __forceinline__ void astore(u32* p, u32 v) {
  __hip_atomic_store(p, v, __ATOMIC_RELAXED, __HIP_MEMORY_SCOPE_AGENT);
}
__device__ __forceinline__ u64 aload64(const u64* p) {
  return __hip_atomic_load(p, __ATOMIC_RELAXED, __HIP_MEMORY_SCOPE_AGENT);
}
__device__ __forceinline__ bool okw(u64 x) {
  return ((u32)x != SENT) && ((u32)(x >> 32) != SENT);
}

// poll two 16B fragments (agent-scope dwordx4 pairs, sc1) until non-sentinel
__device__ __forceinline__ void poll2x(const u32* p0, const u32* p1, f16x8& a, f16x8& b) {
  union { f16x8 v; u32 d[4]; } ua, ub;
  int guard = 0;
  do {
    asm volatile("global_load_dwordx4 %0, %2, off sc1\n\t"
                 "global_load_dwordx4 %1, %3, off sc1\n\t"
                 "s_waitcnt vmcnt(0)"
                 : "=&v"(ua.v), "=&v"(ub.v) : "v"(p0), "v"(p1) : "memory");
    if ((ua.d[0] != SENT) & (ua.d[1] != SENT) & (ua.d[2] != SENT) & (ua.d[3] != SENT) &
        (ub.d[0] != SENT) & (ub.d[1] != SENT) & (ub.d[2] != SENT) & (ub.d[3] != SENT)) break;
  } while (++guard < (1 << 17));   // timeout => junk => absmax fail, no hang
  a = ua.v; b = ub.v;
}

union uf16 { f16 f; u16 u; };

// fragment-linear f16-element index for (k, col), BS=16 cols
__device__ __forceinline__ int fl_idx(int k, int col) {
  return (((k >> 5) * 64 + (((k >> 3) & 3) * 16) + col) << 3) + (k & 7);
}

// -------- pre-pass: gather emb -> fragment-linear f16 xb[g][t] --------
__global__ void __launch_bounds__(256) xb_fill(
    const int* __restrict__ texts, const float* __restrict__ emb,
    f16x8* __restrict__ xb)
{
  const int bidx = blockIdx.x;        // g*Sn + t
  const int g = bidx >> 9, t = bidx & (Sn - 1);
  const int tid = threadIdx.x;
  f16x8* dst = xb + (size_t)bidx * 1024;
  for (int slot = tid; slot < 1024; slot += 256) {
    int s = slot >> 6, sl = slot & 63, kg = sl >> 4, b = sl & 15;
    int idx = texts[t * Bn + g * BS + b];
    const float* er = emb + (size_t)idx * En + s * 32 + kg * 8;
    f16x8 v;
    #pragma unroll
    for (int j = 0; j < 8; ++j) v[j] = (f16)er[j];
    dst[slot] = v;
  }
}

__global__ void __launch_bounds__(NT) lstm_mfma(
    const float* __restrict__ Wf, const float* __restrict__ bf,
    const float* __restrict__ Wi, const float* __restrict__ bi,
    const float* __restrict__ Wo, const float* __restrict__ bo,
    const float* __restrict__ Wc, const float* __restrict__ bc,
    const float* __restrict__ Wy, const float* __restrict__ by,
    float* __restrict__ out, const f16x8* __restrict__ xb,
    u32* __restrict__ ringBase)
{
  __shared__ f16x8 sWAh[4][16][64];    // L0 h-part A-frags, 64 KB
  __shared__ float sAccP[8][64][17];   // per-wave partials, 34.8 KB
  __shared__ float sAccX[64][17];      // x-projection (full-K per mtile), 4.3 KB
  __shared__ float sBiasX[64], sBias1[64];
  __shared__ float sC[16][16];
  __shared__ float sRed[16][2][4];

  const int tid = threadIdx.x;
  const int bid = blockIdx.x;
  const int g = bid & 3;
  const int rank = bid >> 2;                // 0..31 within group
  const int w = tid >> 6, l = tid & 63;
  const int col = l & 15, rb = (l >> 4) << 2;

  const float* Wg[4] = {Wf, Wi, Wc, Wo};
  const float* Bg[4] = {bf, bi, bc, bo};

  u32* ringG = ringBase + (size_t)g * RING * 4096;   // u32 units, 16 KB per buffer
  const f16x8* xbG = xb + (size_t)g * Sn * 1024;

  // ---- prologue: L0 h-part A-frags (K=512, all 4 mtiles) into LDS ----
  for (int i = 0; i < 8; ++i) {
    int slot = tid * 8 + i;               // 4096 slots: [m4][s16][sl]
    int sl = slot & 63, ss = (slot >> 6) & 15, m4 = slot >> 10;
    const float* row = Wg[m4] + (size_t)(rank * RPB + (sl & 15)) * (En + Hn);
    int k0 = ss * 32 + (sl >> 4) * 8;
    f16x8 v;
    #pragma unroll
    for (int j = 0; j < 8; ++j) v[j] = (f16)row[k0 + j];
    sWAh[m4][ss][sl] = v;
  }
  // L1 folded A-frags in VGPRs: wave w needs s in {2w, 2w+1}, all 4 mtiles
  f16x8 afr1[4][2];
  #pragma unroll
  for (int m = 0; m < 4; ++m) {
    const float* row = Wg[m] + (size_t)(Hn + rank * RPB + (l & 15)) * (En + Hn);
    #pragma unroll
    for (int i = 0; i < 2; ++i) {
      int k0 = (2 * w + i) * 32 + (l >> 4) * 8;
      f16x8 v;
      #pragma unroll
      for (int j = 0; j < 8; ++j) v[j] = (f16)(row[k0 + j] + row[k0 + j + Hn]);
      afr1[m][i] = v;
    }
  }
  // L0 x-part A-frags in VGPRs (full 16 ksteps; waves 4..7, mtile = w-4)
  f16x8 axf[16];
  if (w >= 4) {
    const float* row = Wg[w - 4] + (size_t)(rank * RPB + (l & 15)) * (En + Hn);
    #pragma unroll
    for (int i = 0; i < 16; ++i) {
      int k0 = Hn + i * 32 + (l >> 4) * 8;
      f16x8 v;
      #pragma unroll
      for (int j = 0; j < 8; ++j) v[j] = (f16)row[k0 + j];
      axf[i] = v;
    }
  }
  if (tid < 64) {
    int gate = tid >> 4, hr = tid & 15;
    sBiasX[tid] = Bg[gate][rank * RPB + hr];
    sBias1[tid] = Bg[gate][Hn + rank * RPB + hr];
  }
  if (tid < 256) sC[tid >> 4][tid & 15] = 0.f;
  __syncthreads();

  // x-projection for t=0 (waves 4-7: mtile w-4, full K, direct cached xb reads)
  if (w >= 4) {
    f32x4 ax = {0.f, 0.f, 0.f, 0.f};
    #pragma unroll
    for (int s = 0; s < 16; ++s)
      ax = __builtin_amdgcn_mfma_f32_16x16x32_f16(axf[s], xbG[s * 64 + l], ax, 0, 0, 0);
    #pragma unroll
    for (int v = 0; v < 4; ++v) sAccX[(w - 4) * 16 + rb + v][col] = ax[v];
  }

  for (int t = 0; t < Sn; ++t) {
    u32* rdA = ringG + (size_t)((2 * t) & 15) * 4096;
    u32* wrA = ringG + (size_t)((2 * t + 1) & 15) * 4096;
    u32* clA = ringG + (size_t)((2 * t + 9) & 15) * 4096;

    // ===== phase A: layer 0, read rdA -> write wrA =====
    if (tid >= 128 && tid < 256) astore(clA + rank * 128 + (tid - 128), SENT);  // re-sentinel
    {
      f16x8 b0, b1;   // K-slices s=2w, 2w+1 — straight to MFMA, no LDS staging
      poll2x(rdA + (2 * w * 64 + l) * 4, rdA + ((2 * w + 1) * 64 + l) * 4, b0, b1);
      f32x4 a0 = {0.f, 0.f, 0.f, 0.f}, a1 = a0, a2 = a0, a3 = a0;
      a0 = __builtin_amdgcn_mfma_f32_16x16x32_f16(sWAh[0][2 * w][l], b0, a0, 0, 0, 0);
      a1 = __builtin_amdgcn_mfma_f32_16x16x32_f16(sWAh[1][2 * w][l], b0, a1, 0, 0, 0);
      a2 = __builtin_amdgcn_mfma_f32_16x16x32_f16(sWAh[2][2 * w][l], b0, a2, 0, 0, 0);
      a3 = __builtin_amdgcn_mfma_f32_16x16x32_f16(sWAh[3][2 * w][l], b0, a3, 0, 0, 0);
      a0 = __builtin_amdgcn_mfma_f32_16x16x32_f16(sWAh[0][2 * w + 1][l], b1, a0, 0, 0, 0);
      a1 = __builtin_amdgcn_mfma_f32_16x16x32_f16(sWAh[1][2 * w + 1][l], b1, a1, 0, 0, 0);
      a2 = __builtin_amdgcn_mfma_f32_16x16x32_f16(sWAh[2][2 * w + 1][l], b1, a2, 0, 0, 0);
      a3 = __builtin_amdgcn_mfma_f32_16x16x32_f16(sWAh[3][2 * w + 1][l], b1, a3, 0, 0, 0);
      #pragma unroll
      for (int v = 0; v < 4; ++v) {
        sAccP[w][ 0 + rb + v][col] = a0[v];
        sAccP[w][16 + rb + v][col] = a1[v];
        sAccP[w][32 + rb + v][col] = a2[v];
        sAccP[w][48 + rb + v][col] = a3[v];
      }
    }
    __syncthreads();
    if (tid < 128) {  // gates L0: 2 rows/thread, 8-partial sums, pack, store
      int q8 = tid >> 4, b = tid & 15;
      u32 pk = 0;
      #pragma unroll
      for (int j = 0; j < 2; ++j) {
        int hr = 2 * q8 + j;
        float af = sAccX[ 0 + hr][b] + sBiasX[ 0 + hr];
        float ai = sAccX[16 + hr][b] + sBiasX[16 + hr];
        float ac = sAccX[32 + hr][b] + sBiasX[32 + hr];
        float ao = sAccX[48 + hr][b] + sBiasX[48 + hr];
        #pragma unroll
        for (int ww = 0; ww < 8; ++ww) {
          af += sAccP[ww][ 0 + hr][b];
          ai += sAccP[ww][16 + hr][b];
          ac += sAccP[ww][32 + hr][b];
          ao += sAccP[ww][48 + hr][b];
        }
        float ft = fsig(af), it = fsig(ai), ch = ftanh(ac), ot = fsig(ao);
        float c = ft * sC[hr][b] + it * ch;
        sC[hr][b] = c;
        uf16 hv; hv.f = (f16)(ot * ftanh(c));
        pk |= (u32)hv.u << (16 * j);
      }
      int k0 = rank * RPB + 2 * q8;
      int slot = (k0 >> 5) * 64 + ((k0 >> 3) & 3) * 16 + b;
      astore(wrA + slot * 4 + (q8 & 3), pk);
    }

    // ===== phase B: layer 1 folded, read wrA -> write wrB =====
    u32* wrB = ringG + (size_t)((2 * t + 2) & 15) * 4096;
    u32* clB = ringG + (size_t)((2 * t + 10) & 15) * 4096;
    if (tid >= 128 && tid < 256) astore(clB + rank * 128 + (tid - 128), SENT);
    {
      f16x8 b0, b1;
      poll2x(wrA + (2 * w * 64 + l) * 4, wrA + ((2 * w + 1) * 64 + l) * 4, b0, b1);
      f32x4 a0 = {0.f, 0.f, 0.f, 0.f}, a1 = a0, a2 = a0, a3 = a0;
      a0 = __builtin_amdgcn_mfma_f32_16x16x32_f16(afr1[0][0], b0, a0, 0, 0, 0);
      a1 = __builtin_amdgcn_mfma_f32_16x16x32_f16(afr1[1][0], b0, a1, 0, 0, 0);
      a2 = __builtin_amdgcn_mfma_f32_16x16x32_f16(afr1[2][0], b0, a2, 0, 0, 0);
      a3 = __builtin_amdgcn_mfma_f32_16x16x32_f16(afr1[3][0], b0, a3, 0, 0, 0);
      a0 = __builtin_amdgcn_mfma_f32_16x16x32_f16(afr1[0][1], b1, a0, 0, 0, 0);
      a1 = __builtin_amdgcn_mfma_f32_16x16x32_f16(afr1[1][1], b1, a1, 0, 0, 0);
      a2 = __builtin_amdgcn_mfma_f32_16x16x32_f16(afr1[2][1], b1, a2, 0, 0, 0);
      a3 = __builtin_amdgcn_mfma_f32_16x16x32_f16(afr1[3][1], b1, a3, 0, 0, 0);
      #pragma unroll
      for (int v = 0; v < 4; ++v) {
        sAccP[w][ 0 + rb + v][col] = a0[v];
        sAccP[w][16 + rb + v][col] = a1[v];
        sAccP[w][32 + rb + v][col] = a2[v];
        sAccP[w][48 + rb + v][col] = a3[v];
      }
    }
    __syncthreads();
    if (tid < 128) {  // gates L1
      int q8 = tid >> 4, b = tid & 15;
      u32 pk = 0;
      #pragma unroll
      for (int j = 0; j < 2; ++j) {
        int hr = 2 * q8 + j;
        float af = sBias1[ 0 + hr];
        float ai = sBias1[16 + hr];
        float ac = sBias1[32 + hr];
        float ao = sBias1[48 + hr];
        #pragma unroll
        for (int ww = 0; ww < 8; ++ww) {
          af += sAccP[ww][ 0 + hr][b];
          ai += sAccP[ww][16 + hr][b];
          ac += sAccP[ww][32 + hr][b];
          ao += sAccP[ww][48 + hr][b];
        }
        float ft = fsig(af), it = fsig(ai), ch = ftanh(ac), ot = fsig(ao);
        float c = ft * sC[hr][b] + it * ch;
        sC[hr][b] = c;
        uf16 hv; hv.f = (f16)(ot * ftanh(c));
        pk |= (u32)hv.u << (16 * j);
      }
      int k0 = rank * RPB + 2 * q8;
      int slot = (k0 >> 5) * 64 + ((k0 >> 3) & 3) * 16 + b;
      astore(wrB + slot * 4 + (q8 & 3), pk);
    }
    // x-projection for t+1 (waves 4-7, direct cached xb reads) — in the poll shadow
    if (w >= 4 && t + 1 < Sn) {
      const f16x8* xbt = xbG + (size_t)(t + 1) * 1024;
      f32x4 ax = {0.f, 0.f, 0.f, 0.f};
      #pragma unroll
      for (int s = 0; s < 16; ++s)
        ax = __builtin_amdgcn_mfma_f32_16x16x32_f16(axf[s], xbt[s * 64 + l], ax, 0, 0, 0);
      #pragma unroll
      for (int v = 0; v < 4; ++v) sAccX[(w - 4) * 16 + rb + v][col] = ax[v];
    }
  }

  // ---------- epilogue: y = h^T Wy^T + by (rank 0; final h = ring[1024%16] = ring[0]) ----------
  __syncthreads();
  if (rank == 0) {
    const u64* fin = (const u64*)ringG;
    u64* dst = (u64*)&sWAh[0][0][0];   // reuse LDS as staging
    for (int i = tid; i < 2048; i += NT) {
      u64 v = aload64(fin + i);
      int guard = 0;
      while (!okw(v)) { v = aload64(fin + i); if (++guard > (1 << 17)) break; }
      dst[i] = v;
    }
  }
  __syncthreads();
  if (rank == 0 && tid < 128) {
    const f16* tmp = (const f16*)&sWAh[0][0][0];
    int b = tid >> 3, o = (tid >> 2) & 1, kc = tid & 3;   // 16 x 2 x 4
    float p = 0.f;
    for (int kk = 0; kk < 128; ++kk) {
      int k = kc * 128 + kk;
      p += (float)tmp[fl_idx(k, b)] * Wy[o * Hn + k];
    }
    sRed[b][o][kc] = p;
  }
  __syncthreads();
  if (rank == 0 && tid < 32) {
    int b2 = tid >> 1, o2 = tid & 1;
    float s = by[o2];
    #pragma unroll
    for (int q = 0; q < 4; ++q) s += sRed[b2][o2][q];
    out[(g * BS + b2) * OUTn + o2] = s;
  }
}

extern "C" void kernel_launch(void* const* d_in, const int* in_sizes, int n_in,
                              void* d_out, int out_size, void* d_ws, size_t ws_size,
                              hipStream_t stream) {
  const int*   texts = (const int*)d_in[0];
  const float* emb   = (const float*)d_in[1];
  const float* Wf    = (const float*)d_in[2];
  const float* bf    = (const float*)d_in[3];
  const float* Wi    = (const float*)d_in[4];
  const float* bi    = (const float*)d_in[5];
  const float* Wo    = (const float*)d_in[6];
  const float* bo    = (const float*)d_in[7];
  const float* Wc    = (const float*)d_in[8];
  const float* bc    = (const float*)d_in[9];
  const float* Wy    = (const float*)d_in[10];
  const float* by    = (const float*)d_in[11];
  float* out = (float*)d_out;

  f16x8* xbuf     = (f16x8*)((char*)d_ws + XB_OFF);
  u32*   ringBase = (u32*)((char*)d_ws + RG_OFF);

  // ring init (captured in graph -> re-established every replay):
  // all 16 buffers sentinel, then ring[g][0] = zeros (initial h).
  hipMemsetAsync((void*)ringBase, 0xFF, RG_SZ, stream);
  for (int g = 0; g < NG; ++g)
    hipMemsetAsync((void*)((char*)ringBase + (size_t)g * RING * 16384), 0x00, 16384, stream);

  xb_fill<<<dim3(NG * Sn), dim3(256), 0, stream>>>(texts, emb, xbuf);

  void* args[] = {(void*)&Wf, (void*)&bf, (void*)&Wi, (void*)&bi,
                  (void*)&Wo, (void*)&bo, (void*)&Wc, (void*)&bc, (void*)&Wy, (void*)&by,
                  (void*)&out, (void*)&xbuf, (void*)&ringBase};
  hipLaunchCooperativeKernel((const void*)lstm_mfma, dim3(NB), dim3(NT), args, 0, stream);
}